// Round 10
// baseline (650.251 us; speedup 1.0000x reference)
//
#include <hip/hip_runtime.h>
#include <math.h>

typedef __bf16 bf16;
typedef __bf16 bf16x8 __attribute__((ext_vector_type(8)));
typedef float f32x4 __attribute__((ext_vector_type(4)));

#define MFMA16(a,b,c) __builtin_amdgcn_mfma_f32_16x16x32_bf16((a),(b),(c),0,0,0)

#define D 256
#define H 4
#define A 32
#define P 4
#define HA 128
#define RHID 64
#define ROWS 64
#define NROWS_TOT 262144
#define SCALE_F 0.17677669529663687f

// ws offsets in bf16 elements
#define OFF_Q  0
#define OFF_F  32768
#define OFF_G1 65536
#define OFF_G2 81920
#define OFF_O  98304
#define NPACK  102400

__device__ __forceinline__ float fast_exp(float x) { return __expf(x); }
__device__ __forceinline__ float fast_rcp(float x) { return __builtin_amdgcn_rcpf(x); }

// ---------------- weight prepack: f32 -> bf16 in MFMA B-fragment order ----------------
__global__ __launch_bounds__(256)
void prep_kernel(const float* __restrict__ Wq, const float* __restrict__ Wf,
                 const float* __restrict__ Wg1, const float* __restrict__ Wg2,
                 const float* __restrict__ Wo, bf16* __restrict__ ws)
{
  int i = blockIdx.x * 256 + threadIdx.x;
  if (i >= NPACK) return;
  float v;
  if (i < OFF_F) {
    int j = i & 7, l = (i >> 3) & 63, nt = (i >> 9) & 1, ks = (i >> 10) & 7, h = i >> 13;
    int k = ks * 32 + (l >> 4) * 8 + j, n = nt * 16 + (l & 15);
    v = Wq[(h * 256 + k) * 32 + n];
  } else if (i < OFF_G1) {
    int ii = i - OFF_F;
    int j = ii & 7, l = (ii >> 3) & 63, g = (ii >> 9) & 15, ks = ii >> 13;
    int k = ks * 32 + (l >> 4) * 8 + j, n = g * 16 + (l & 15);
    v = Wf[k * 256 + n];
  } else if (i < OFF_G2) {
    int ii = i - OFF_G1;
    int j = ii & 7, l = (ii >> 3) & 63, nt = (ii >> 9) & 3, ks = ii >> 11;
    int k = ks * 32 + (l >> 4) * 8 + j, n = nt * 16 + (l & 15);
    v = Wg1[k * 64 + n];
  } else if (i < OFF_O) {
    int ii = i - OFF_G2;
    int j = ii & 7, l = (ii >> 3) & 63, g = (ii >> 9) & 15, ks = ii >> 13;
    int k = ks * 32 + (l >> 4) * 8 + j, n = g * 16 + (l & 15);
    v = Wg2[k * 256 + n];
  } else {
    int ii = i - OFF_O;
    int j = ii & 7, l = (ii >> 3) & 63, nt = (ii >> 9) & 1, h = ii >> 10;
    int k = (l >> 4) * 8 + j, n = nt * 16 + (l & 15);
    v = Wo[(h * 32 + k) * 32 + n];
  }
  ws[i] = (bf16)v;
}

// ---------------- fused main kernel ----------------
// Register-lean redesign: mt-chunked GEMM2/GEMM4 (16-reg accs), out_pre held as bf16x8[8]
// (32 VGPR), final LN via two-pass GEMM4 recompute (no val storage). Target: total
// (arch+accum) regs <= 128 -> 4 waves/SIMD; LDS ~40KB -> 4 blocks/CU.
__global__ __launch_bounds__(256, 4)
void faiia_kernel(const float* __restrict__ x, const float* __restrict__ mp,
    const float* __restrict__ bq, const float* __restrict__ pk,
    const float* __restrict__ pv, const float* __restrict__ imp,
    const float* __restrict__ fa, const float* __restrict__ ft,
    const float* __restrict__ bo, const float* __restrict__ lng,
    const float* __restrict__ lnb, const float* __restrict__ bfb,
    const float* __restrict__ Wg1, const float* __restrict__ bg1,
    const float* __restrict__ bg2, const float* __restrict__ lnFg,
    const float* __restrict__ lnFb, const bf16* __restrict__ ws,
    float* __restrict__ out)
{
  // regA (32KB) timeline:
  //  xfrag(full) -> q(upper 16KB, swizzled) + attfrag(lower 16KB) -> combfrag(upper 16KB)
  //  -> opfrag(full) -> hfrag(bytes 0..8191) + LN scratch (bytes 8192..10560)
  __shared__ __attribute__((aligned(16))) bf16 s_regA[16384];
  __shared__ float s_pk[H*P*A], s_pv[H*P*A], s_imp[H*P], s_fa[H], s_ft[H];
  __shared__ bf16 s_bq[HA], s_bo[HA], s_lng[HA], s_lnb[HA];
  __shared__ bf16 s_bf[D], s_bg2[D], s_lnFg[D], s_lnFb[D];
  __shared__ float s_bg1[RHID], s_wg1d[RHID];
  __shared__ float s_diff[ROWS];

  bf16* s_q = s_regA + 8192;                                 // upper 16KB
  float* s_lnsum = reinterpret_cast<float*>(s_regA + 4096);  // byte 8192 (dead after GEMM3)
  float* s_lnsq  = s_lnsum + 256;
  float* s_rmean = s_lnsq + 256;
  float* s_rrstd = s_rmean + 64;

  const int t = threadIdx.x;
  const int lane = t & 63;
  const int w = t >> 6;
  const int lr = lane >> 4;
  const int lc = lane & 15;
  const int row0 = blockIdx.x * ROWS;

  // ---- stage small constants ----
  for (int i = t; i < H*P*A; i += 256) { s_pk[i] = pk[i]; s_pv[i] = pv[i]; }
  if (t < H*P) s_imp[t] = imp[t];
  if (t < H) { s_fa[t] = fa[t]; s_ft[t] = ft[t]; }
  if (t < HA) { s_bq[t] = (bf16)bq[t]; s_bo[t] = (bf16)bo[t];
                s_lng[t] = (bf16)lng[t]; s_lnb[t] = (bf16)lnb[t]; }
  s_bf[t] = (bf16)bfb[t]; s_bg2[t] = (bf16)bg2[t];
  s_lnFg[t] = (bf16)lnFg[t]; s_lnFb[t] = (bf16)lnFb[t];
  if (t < RHID) { s_bg1[t] = bg1[t]; s_wg1d[t] = Wg1[256*RHID + t]; }
  if (t < ROWS) { float m = mp[row0 + t]; s_diff[t] = 1.f - 2.f*fabsf(m - 0.5f); }

  // ---- stage x -> bf16 A-fragments: slot s = (mt*8+ks)*64 + l ----
  {
    const float* xbase = x + (size_t)row0 * D;
    #pragma unroll
    for (int i = 0; i < 8; ++i) {
      int s = t + 256*i;
      int l = s & 63, ks = (s >> 6) & 7, mt = s >> 9;
      int row = mt*16 + (l & 15);
      int k0 = ks*32 + ((l >> 4) & 3)*8;
      const float* xp = xbase + row*D + k0;
      float4 v0 = *reinterpret_cast<const float4*>(xp);
      float4 v1 = *reinterpret_cast<const float4*>(xp + 4);
      bf16x8 fr;
      fr[0]=(bf16)v0.x; fr[1]=(bf16)v0.y; fr[2]=(bf16)v0.z; fr[3]=(bf16)v0.w;
      fr[4]=(bf16)v1.x; fr[5]=(bf16)v1.y; fr[6]=(bf16)v1.z; fr[7]=(bf16)v1.w;
      *reinterpret_cast<bf16x8*>(&s_regA[(size_t)s * 8]) = fr;
    }
  }
  __syncthreads();   // B1

  // ---- GEMM1: Q = X(64x256) * Wq[head=w](256x32) ----
  {
    f32x4 acc[4][2];
    #pragma unroll
    for (int mt = 0; mt < 4; ++mt) { acc[mt][0] = (f32x4)0.f; acc[mt][1] = (f32x4)0.f; }
    const bf16x8* pQ = reinterpret_cast<const bf16x8*>(ws + OFF_Q);
    #pragma unroll
    for (int ks = 0; ks < 8; ++ks) {
      bf16x8 b0 = pQ[((w*8 + ks)*2 + 0)*64 + lane];
      bf16x8 b1 = pQ[((w*8 + ks)*2 + 1)*64 + lane];
      #pragma unroll
      for (int mt = 0; mt < 4; ++mt) {
        bf16x8 a = *reinterpret_cast<const bf16x8*>(&s_regA[((mt*8 + ks)*64 + lane)*8]);
        acc[mt][0] = MFMA16(a, b0, acc[mt][0]);
        acc[mt][1] = MFMA16(a, b1, acc[mt][1]);
      }
    }
    __syncthreads();   // B2: all xfrag reads done
    float bq0 = (float)s_bq[w*32 + lc], bq1 = (float)s_bq[w*32 + 16 + lc];
    #pragma unroll
    for (int mt = 0; mt < 4; ++mt)
      #pragma unroll
      for (int r = 0; r < 4; ++r) {
        int row = mt*16 + lr*4 + r;
        int sw = (row & 7) << 3;
        int c0 = (w*32 + lc) ^ sw;
        int c1 = (w*32 + 16 + lc) ^ sw;
        s_q[row*128 + c0] = (bf16)(acc[mt][0][r] + bq0);
        s_q[row*128 + c1] = (bf16)(acc[mt][1][r] + bq1);
      }
  }
  // no barrier: q and attfrag are intra-wave from here (wave w = head w)

  // ---- attention: wave w = head w, lane = row ----
  {
    const int r = lane;
    const int h = w;
    const int swr = (r & 7) << 3;
    float q[32];
    #pragma unroll
    for (int g = 0; g < 4; ++g) {
      bf16x8 v = *reinterpret_cast<const bf16x8*>(&s_q[r*128 + ((h*32 + g*8) ^ swr)]);
      #pragma unroll
      for (int j = 0; j < 8; ++j) q[g*8 + j] = (float)v[j];
    }
    float u = s_diff[r];
    float up = u + 1e-8f;
    float mod = 1.f + s_fa[h]*up*up*s_ft[h];
    float sc[4];
    #pragma unroll
    for (int p = 0; p < 4; ++p) {
      float s = s_imp[h*4 + p];
      const float4* kp = reinterpret_cast<const float4*>(&s_pk[(h*4 + p)*32]);
      #pragma unroll
      for (int g = 0; g < 8; ++g) {
        float4 kv = kp[g];
        s = fmaf(q[g*4+0], kv.x, s); s = fmaf(q[g*4+1], kv.y, s);
        s = fmaf(q[g*4+2], kv.z, s); s = fmaf(q[g*4+3], kv.w, s);
      }
      sc[p] = s * mod * SCALE_F;
    }
    float mx = fmaxf(fmaxf(sc[0], sc[1]), fmaxf(sc[2], sc[3]));
    float e0 = fast_exp(sc[0]-mx), e1 = fast_exp(sc[1]-mx);
    float e2 = fast_exp(sc[2]-mx), e3 = fast_exp(sc[3]-mx);
    float inv = fast_rcp(e0+e1+e2+e3);
    e0 *= inv; e1 *= inv; e2 *= inv; e3 *= inv;
    const float4* p0 = reinterpret_cast<const float4*>(&s_pv[(h*4+0)*32]);
    const float4* p1 = reinterpret_cast<const float4*>(&s_pv[(h*4+1)*32]);
    const float4* p2 = reinterpret_cast<const float4*>(&s_pv[(h*4+2)*32]);
    const float4* p3 = reinterpret_cast<const float4*>(&s_pv[(h*4+3)*32]);
    const int mt = r >> 4, rl = r & 15;
    #pragma unroll
    for (int g = 0; g < 4; ++g) {
      float4 a0 = p0[g*2],   b0v = p0[g*2+1];
      float4 a1 = p1[g*2],   b1v = p1[g*2+1];
      float4 a2 = p2[g*2],   b2v = p2[g*2+1];
      float4 a3 = p3[g*2],   b3v = p3[g*2+1];
      bf16x8 av;
      av[0] = (bf16)(e0*a0.x + e1*a1.x + e2*a2.x + e3*a3.x);
      av[1] = (bf16)(e0*a0.y + e1*a1.y + e2*a2.y + e3*a3.y);
      av[2] = (bf16)(e0*a0.z + e1*a1.z + e2*a2.z + e3*a3.z);
      av[3] = (bf16)(e0*a0.w + e1*a1.w + e2*a2.w + e3*a3.w);
      av[4] = (bf16)(e0*b0v.x + e1*b1v.x + e2*b2v.x + e3*b3v.x);
      av[5] = (bf16)(e0*b0v.y + e1*b1v.y + e2*b2v.y + e3*b3v.y);
      av[6] = (bf16)(e0*b0v.z + e1*b1v.z + e2*b2v.z + e3*b3v.z);
      av[7] = (bf16)(e0*b0v.w + e1*b1v.w + e2*b2v.w + e3*b3v.w);
      *reinterpret_cast<bf16x8*>(&s_regA[(((w*4) + mt)*64 + g*16 + rl)*8]) = av;
    }
  }
  __syncthreads();   // B3: all q reads done -> comb may overwrite upper region

  // ---- Wo-GEMM + per-head LN -> combfrag (upper 16KB) ----
  {
    const bf16x8* pO = reinterpret_cast<const bf16x8*>(ws + OFF_O);
    bf16x8 b0 = pO[(w*2 + 0)*64 + lane];
    bf16x8 b1 = pO[(w*2 + 1)*64 + lane];
    f32x4 acc[4][2];
    #pragma unroll
    for (int mt = 0; mt < 4; ++mt) { acc[mt][0] = (f32x4)0.f; acc[mt][1] = (f32x4)0.f; }
    #pragma unroll
    for (int mt = 0; mt < 4; ++mt) {
      bf16x8 a = *reinterpret_cast<const bf16x8*>(&s_regA[((w*4 + mt)*64 + lane)*8]);
      acc[mt][0] = MFMA16(a, b0, acc[mt][0]);
      acc[mt][1] = MFMA16(a, b1, acc[mt][1]);
    }
    float bo0 = (float)s_bo[w*32 + lc],  bo1 = (float)s_bo[w*32 + 16 + lc];
    float lg0 = (float)s_lng[w*32 + lc], lg1 = (float)s_lng[w*32 + 16 + lc];
    float lb0 = (float)s_lnb[w*32 + lc], lb1 = (float)s_lnb[w*32 + 16 + lc];
    #pragma unroll
    for (int mt = 0; mt < 4; ++mt)
      #pragma unroll
      for (int r = 0; r < 4; ++r) {
        float v0 = acc[mt][0][r] + bo0;
        float v1 = acc[mt][1][r] + bo1;
        float s = v0 + v1, sq = v0*v0 + v1*v1;
        s += __shfl_xor(s, 1, 64);  sq += __shfl_xor(sq, 1, 64);
        s += __shfl_xor(s, 2, 64);  sq += __shfl_xor(sq, 2, 64);
        s += __shfl_xor(s, 4, 64);  sq += __shfl_xor(sq, 4, 64);
        s += __shfl_xor(s, 8, 64);  sq += __shfl_xor(sq, 8, 64);
        float mean = s * (1.f/32.f);
        float var  = sq * (1.f/32.f) - mean*mean;
        float rstd = rsqrtf(var + 1e-5f);
        float n0 = (v0 - mean)*rstd*lg0 + lb0;
        float n1 = (v1 - mean)*rstd*lg1 + lb1;
        int rl = lr*4 + r;
        int base = 8192 + ((w*4 + mt)*64)*8;
        s_regA[base + (16*(lc >> 3)       + rl)*8 + (lane & 7)] = (bf16)n0;
        s_regA[base + (16*(2 + (lc >> 3)) + rl)*8 + (lane & 7)] = (bf16)n1;
      }
  }
  __syncthreads();   // B4: combfrag ready

  // ---- GEMM2 (mt-chunked): out_pre = combined(64x128)*Wf(128x256); kept as bf16 regs ----
  bf16x8 opb[8];     // out_pre bf16: opb[2*mt + (nt>>1)][(nt&1)*4 + r]
  {
    const bf16x8* pF = reinterpret_cast<const bf16x8*>(ws + OFF_F);
    #pragma unroll
    for (int mt = 0; mt < 4; ++mt) {
      f32x4 acc[4];
      #pragma unroll
      for (int nt = 0; nt < 4; ++nt) acc[nt] = (f32x4)0.f;
      #pragma unroll
      for (int ks = 0; ks < 4; ++ks) {
        bf16x8 a = *reinterpret_cast<const bf16x8*>(&s_regA[8192 + ((ks*4 + mt)*64 + lane)*8]);
        #pragma unroll
        for (int nt = 0; nt < 4; ++nt)
          acc[nt] = MFMA16(a, pF[(ks*16 + w*4 + nt)*64 + lane], acc[nt]);
      }
      bf16x8 o0, o1;
      #pragma unroll
      for (int nt = 0; nt < 4; ++nt) {
        float bfv = (float)s_bf[w*64 + nt*16 + lc];
        #pragma unroll
        for (int r = 0; r < 4; ++r) {
          float v = acc[nt][r] + bfv;
          if (nt == 0) o0[r] = (bf16)v;
          else if (nt == 1) o0[4 + r] = (bf16)v;
          else if (nt == 2) o1[r] = (bf16)v;
          else o1[4 + r] = (bf16)v;
        }
      }
      opb[2*mt] = o0; opb[2*mt + 1] = o1;
    }
  }
  __syncthreads();   // B5: all combfrag reads done -> opfrag may overwrite full regA

  // ---- opfrag write (from bf16 regs) ----
  {
    #pragma unroll
    for (int mt = 0; mt < 4; ++mt)
      #pragma unroll
      for (int nt = 0; nt < 4; ++nt) {
        int ks3 = w*2 + (nt >> 1);
        #pragma unroll
        for (int r = 0; r < 4; ++r) {
          int lane2 = 16*((nt & 1)*2 + (lc >> 3)) + (lr*4 + r);
          s_regA[((ks3*4 + mt)*64 + lane2)*8 + (lane & 7)] = opb[2*mt + (nt >> 1)][(nt & 1)*4 + r];
        }
      }
  }
  __syncthreads();   // B6: opfrag ready

  // ---- GEMM3: hidden = relu(out_pre(64x256)*Wg1(256x64)+diff*wg1d+bg1) ----
  {
    f32x4 acc3[4];
    #pragma unroll
    for (int mt = 0; mt < 4; ++mt) acc3[mt] = (f32x4)0.f;
    const bf16x8* pG1 = reinterpret_cast<const bf16x8*>(ws + OFF_G1);
    #pragma unroll
    for (int ks = 0; ks < 8; ++ks) {
      bf16x8 b = pG1[(ks*4 + w)*64 + lane];
      #pragma unroll
      for (int mt = 0; mt < 4; ++mt) {
        bf16x8 a = *reinterpret_cast<const bf16x8*>(&s_regA[((ks*4 + mt)*64 + lane)*8]);
        acc3[mt] = MFMA16(a, b, acc3[mt]);
      }
    }
    int col3 = w*16 + lc;
    float b1v = s_bg1[col3], wdv = s_wg1d[col3];
    #pragma unroll
    for (int mt = 0; mt < 4; ++mt)
      #pragma unroll
      for (int r = 0; r < 4; ++r) {
        int row = mt*16 + lr*4 + r;
        acc3[mt][r] = fmaxf(acc3[mt][r] + b1v + s_diff[row]*wdv, 0.f);
      }
    __syncthreads();   // B7: all opfrag reads done -> hfrag may overwrite regA[0:8KB)
    #pragma unroll
    for (int mt = 0; mt < 4; ++mt)
      #pragma unroll
      for (int r = 0; r < 4; ++r)
        s_regA[(((w >> 1)*4 + mt)*64 + 16*((w & 1)*2 + (lc >> 3)) + (lr*4 + r))*8 + (lane & 7)] = (bf16)acc3[mt][r];
  }
  __syncthreads();   // B8: hfrag ready

  // ---- GEMM4 pass 1 (mt-chunked): stats only ----
  {
    const float* xbase = x + (size_t)row0 * D;
    const bf16x8* pG2 = reinterpret_cast<const bf16x8*>(ws + OFF_G2);
    #pragma unroll
    for (int mt = 0; mt < 4; ++mt) {
      f32x4 acc4[4];
      #pragma unroll
      for (int nt = 0; nt < 4; ++nt) acc4[nt] = (f32x4)0.f;
      #pragma unroll
      for (int ks = 0; ks < 2; ++ks) {
        bf16x8 a = *reinterpret_cast<const bf16x8*>(&s_regA[((ks*4 + mt)*64 + lane)*8]);
        #pragma unroll
        for (int nt = 0; nt < 4; ++nt)
          acc4[nt] = MFMA16(a, pG2[(ks*16 + w*4 + nt)*64 + lane], acc4[nt]);
      }
      float s4[4] = {0.f,0.f,0.f,0.f}, q4[4] = {0.f,0.f,0.f,0.f};
      #pragma unroll
      for (int nt = 0; nt < 4; ++nt) {
        int c = w*64 + nt*16 + lc;
        float bg2v = (float)s_bg2[c];
        #pragma unroll
        for (int r = 0; r < 4; ++r) {
          int row = mt*16 + lr*4 + r;
          float z = acc4[nt][r] + bg2v;
          float gate = fast_rcp(1.f + fast_exp(-z));
          float op = (float)opb[2*mt + (nt >> 1)][(nt & 1)*4 + r];
          float val = op*gate + xbase[row*D + c];
          s4[r] += val; q4[r] = fmaf(val, val, q4[r]);
        }
      }
      #pragma unroll
      for (int r = 0; r < 4; ++r) {
        float s = s4[r], q = q4[r];
        s += __shfl_xor(s, 1, 64);  q += __shfl_xor(q, 1, 64);
        s += __shfl_xor(s, 2, 64);  q += __shfl_xor(q, 2, 64);
        s += __shfl_xor(s, 4, 64);  q += __shfl_xor(q, 4, 64);
        s += __shfl_xor(s, 8, 64);  q += __shfl_xor(q, 8, 64);
        if (lc == 0) {
          int row = mt*16 + lr*4 + r;
          s_lnsum[row*4 + w] = s;
          s_lnsq[row*4 + w]  = q;
        }
      }
    }
  }
  __syncthreads();   // B9: LN partials ready
  if (t < ROWS) {
    float s  = s_lnsum[t*4] + s_lnsum[t*4+1] + s_lnsum[t*4+2] + s_lnsum[t*4+3];
    float sq = s_lnsq[t*4]  + s_lnsq[t*4+1]  + s_lnsq[t*4+2]  + s_lnsq[t*4+3];
    float mean = s * (1.f/256.f);
    float var  = sq * (1.f/256.f) - mean*mean;
    s_rmean[t] = mean;
    s_rrstd[t] = rsqrtf(var + 1e-5f);
  }
  __syncthreads();   // B10: stats ready

  // ---- GEMM4 pass 2 (recompute, bit-identical val) + scale + store ----
  {
    const float* xbase = x + (size_t)row0 * D;
    float* obase = out + (size_t)row0 * D;
    const bf16x8* pG2 = reinterpret_cast<const bf16x8*>(ws + OFF_G2);
    #pragma unroll
    for (int mt = 0; mt < 4; ++mt) {
      f32x4 acc4[4];
      #pragma unroll
      for (int nt = 0; nt < 4; ++nt) acc4[nt] = (f32x4)0.f;
      #pragma unroll
      for (int ks = 0; ks < 2; ++ks) {
        bf16x8 a = *reinterpret_cast<const bf16x8*>(&s_regA[((ks*4 + mt)*64 + lane)*8]);
        #pragma unroll
        for (int nt = 0; nt < 4; ++nt)
          acc4[nt] = MFMA16(a, pG2[(ks*16 + w*4 + nt)*64 + lane], acc4[nt]);
      }
      float mean4[4], rstd4[4];
      #pragma unroll
      for (int r = 0; r < 4; ++r) {
        int row = mt*16 + lr*4 + r;
        mean4[r] = s_rmean[row];
        rstd4[r] = s_rrstd[row];
      }
      #pragma unroll
      for (int nt = 0; nt < 4; ++nt) {
        int c = w*64 + nt*16 + lc;
        float bg2v = (float)s_bg2[c];
        float g_ = (float)s_lnFg[c], b_ = (float)s_lnFb[c];
        #pragma unroll
        for (int r = 0; r < 4; ++r) {
          int row = mt*16 + lr*4 + r;
          float z = acc4[nt][r] + bg2v;
          float gate = fast_rcp(1.f + fast_exp(-z));
          float op = (float)opb[2*mt + (nt >> 1)][(nt & 1)*4 + r];
          float val = op*gate + xbase[row*D + c];
          obase[row*D + c] = (val - mean4[r])*rstd4[r]*g_ + b_;
        }
      }
    }
  }
}

extern "C" void kernel_launch(void* const* d_in, const int* in_sizes, int n_in,
                              void* d_out, int out_size, void* d_ws, size_t ws_size,
                              hipStream_t stream) {
  (void)in_sizes; (void)n_in; (void)ws_size; (void)out_size;
  const float* x   = (const float*)d_in[0];
  const float* mp  = (const float*)d_in[1];
  const float* Wq  = (const float*)d_in[2];
  const float* bq  = (const float*)d_in[3];
  const float* pk  = (const float*)d_in[4];
  const float* pv  = (const float*)d_in[5];
  const float* imp = (const float*)d_in[6];
  const float* fa  = (const float*)d_in[7];
  const float* ft  = (const float*)d_in[8];
  const float* Wo  = (const float*)d_in[9];
  const float* bo  = (const float*)d_in[10];
  const float* lng = (const float*)d_in[11];
  const float* lnb = (const float*)d_in[12];
  const float* Wf  = (const float*)d_in[13];
  const float* bf  = (const float*)d_in[14];
  const float* Wg1 = (const float*)d_in[15];
  const float* bg1 = (const float*)d_in[16];
  const float* Wg2 = (const float*)d_in[17];
  const float* bg2 = (const float*)d_in[18];
  const float* lnFg= (const float*)d_in[19];
  const float* lnFb= (const float*)d_in[20];
  float* out = (float*)d_out;
  bf16* ws = (bf16*)d_ws;

  hipLaunchKernelGGL(prep_kernel, dim3((NPACK + 255)/256), dim3(256), 0, stream,
                     Wq, Wf, Wg1, Wg2, Wo, ws);
  hipLaunchKernelGGL(faiia_kernel, dim3(NROWS_TOT / ROWS), dim3(256), 0, stream,
                     x, mp, bq, pk, pv, imp, fa, ft, bo, lng, lnb,
                     bf, Wg1, bg1, bg2, lnFg, lnFb, ws, out);
}

// Round 11
// 472.343 us; speedup vs baseline: 1.3766x; 1.3766x over previous
//
#include <hip/hip_runtime.h>
#include <math.h>

typedef __bf16 bf16;
typedef __bf16 bf16x8 __attribute__((ext_vector_type(8)));
typedef float f32x4 __attribute__((ext_vector_type(4)));

#define MFMA16(a,b,c) __builtin_amdgcn_mfma_f32_16x16x32_bf16((a),(b),(c),0,0,0)

#define D 256
#define H 4
#define A 32
#define P 4
#define HA 128
#define RHID 64
#define ROWS 64
#define NROWS_TOT 262144
#define SCALE_F 0.17677669529663687f

// ws offsets in bf16 elements
#define OFF_Q  0
#define OFF_F  32768
#define OFF_G1 65536
#define OFF_G2 81920
#define OFF_O  98304
#define NPACK  102400

__device__ __forceinline__ float fast_exp(float x) { return __expf(x); }
__device__ __forceinline__ float fast_rcp(float x) { return __builtin_amdgcn_rcpf(x); }

// ---------------- weight prepack: f32 -> bf16 in MFMA B-fragment order ----------------
__global__ __launch_bounds__(256)
void prep_kernel(const float* __restrict__ Wq, const float* __restrict__ Wf,
                 const float* __restrict__ Wg1, const float* __restrict__ Wg2,
                 const float* __restrict__ Wo, bf16* __restrict__ ws)
{
  int i = blockIdx.x * 256 + threadIdx.x;
  if (i >= NPACK) return;
  float v;
  if (i < OFF_F) {
    int j = i & 7, l = (i >> 3) & 63, nt = (i >> 9) & 1, ks = (i >> 10) & 7, h = i >> 13;
    int k = ks * 32 + (l >> 4) * 8 + j, n = nt * 16 + (l & 15);
    v = Wq[(h * 256 + k) * 32 + n];
  } else if (i < OFF_G1) {
    int ii = i - OFF_F;
    int j = ii & 7, l = (ii >> 3) & 63, g = (ii >> 9) & 15, ks = ii >> 13;
    int k = ks * 32 + (l >> 4) * 8 + j, n = g * 16 + (l & 15);
    v = Wf[k * 256 + n];
  } else if (i < OFF_G2) {
    int ii = i - OFF_G1;
    int j = ii & 7, l = (ii >> 3) & 63, nt = (ii >> 9) & 3, ks = ii >> 11;
    int k = ks * 32 + (l >> 4) * 8 + j, n = nt * 16 + (l & 15);
    v = Wg1[k * 64 + n];
  } else if (i < OFF_O) {
    int ii = i - OFF_G2;
    int j = ii & 7, l = (ii >> 3) & 63, g = (ii >> 9) & 15, ks = ii >> 13;
    int k = ks * 32 + (l >> 4) * 8 + j, n = g * 16 + (l & 15);
    v = Wg2[k * 256 + n];
  } else {
    int ii = i - OFF_O;
    int j = ii & 7, l = (ii >> 3) & 63, nt = (ii >> 9) & 1, h = ii >> 10;
    int k = (l >> 4) * 8 + j, n = nt * 16 + (l & 15);
    v = Wo[(h * 32 + k) * 32 + n];
  }
  ws[i] = (bf16)v;
}

// ---------------- fused main kernel ----------------
// Front half (GEMM1/attn/Wo): head-partitioned, 3 barriers. Back half (GEMM2..store):
// ROW-partitioned (wave w owns rows w*16..w*16+15), fully wave-local after B4:
// private 8KB LDS slice for opfrag/hfrag transposes, out_pre as bf16 regs (opb),
// LN via intra-wave shfl + GEMM4 two-pass recompute. 5 barriers total (was 12).
// __launch_bounds__(256,2): only bound that avoids spills (R3/R6/R10).
__global__ __launch_bounds__(256, 2)
void faiia_kernel(const float* __restrict__ x, const float* __restrict__ mp,
    const float* __restrict__ bq, const float* __restrict__ pk,
    const float* __restrict__ pv, const float* __restrict__ imp,
    const float* __restrict__ fa, const float* __restrict__ ft,
    const float* __restrict__ bo, const float* __restrict__ lng,
    const float* __restrict__ lnb, const float* __restrict__ bfb,
    const float* __restrict__ Wg1, const float* __restrict__ bg1,
    const float* __restrict__ bg2, const float* __restrict__ lnFg,
    const float* __restrict__ lnFb, const bf16* __restrict__ ws,
    float* __restrict__ out)
{
  // regA (32KB) timeline:
  //  xfrag(full) -> [B2] q(upper, swizzled)+attfrag(lower) -> [B3a] combfrag(upper)
  //  -> [B3b] GEMM2 reads -> [B4] per-wave 8KB slices (opfrag -> hfrag)
  __shared__ __attribute__((aligned(16))) bf16 s_regA[16384];
  __shared__ float s_pk[H*P*A], s_pv[H*P*A], s_imp[H*P], s_fa[H], s_ft[H];
  __shared__ bf16 s_bq[HA], s_bo[HA], s_lng[HA], s_lnb[HA];
  __shared__ bf16 s_bf[D], s_bg2[D], s_lnFg[D], s_lnFb[D];
  __shared__ float s_bg1[RHID], s_wg1d[RHID];
  __shared__ float s_diff[ROWS];

  bf16* s_q = s_regA + 8192;     // upper 16KB (elements)

  const int t = threadIdx.x;
  const int lane = t & 63;
  const int w = t >> 6;
  const int lr = lane >> 4;
  const int lc = lane & 15;
  const int row0 = blockIdx.x * ROWS;

  // ---- stage small constants ----
  for (int i = t; i < H*P*A; i += 256) { s_pk[i] = pk[i]; s_pv[i] = pv[i]; }
  if (t < H*P) s_imp[t] = imp[t];
  if (t < H) { s_fa[t] = fa[t]; s_ft[t] = ft[t]; }
  if (t < HA) { s_bq[t] = (bf16)bq[t]; s_bo[t] = (bf16)bo[t];
                s_lng[t] = (bf16)lng[t]; s_lnb[t] = (bf16)lnb[t]; }
  s_bf[t] = (bf16)bfb[t]; s_bg2[t] = (bf16)bg2[t];
  s_lnFg[t] = (bf16)lnFg[t]; s_lnFb[t] = (bf16)lnFb[t];
  if (t < RHID) { s_bg1[t] = bg1[t]; s_wg1d[t] = Wg1[256*RHID + t]; }
  if (t < ROWS) { float m = mp[row0 + t]; s_diff[t] = 1.f - 2.f*fabsf(m - 0.5f); }

  // ---- stage x -> bf16 A-fragments: slot s = (mt*8+ks)*64 + l ----
  {
    const float* xbase = x + (size_t)row0 * D;
    #pragma unroll
    for (int i = 0; i < 8; ++i) {
      int s = t + 256*i;
      int l = s & 63, ks = (s >> 6) & 7, mt = s >> 9;
      int row = mt*16 + (l & 15);
      int k0 = ks*32 + ((l >> 4) & 3)*8;
      const float* xp = xbase + row*D + k0;
      float4 v0 = *reinterpret_cast<const float4*>(xp);
      float4 v1 = *reinterpret_cast<const float4*>(xp + 4);
      bf16x8 fr;
      fr[0]=(bf16)v0.x; fr[1]=(bf16)v0.y; fr[2]=(bf16)v0.z; fr[3]=(bf16)v0.w;
      fr[4]=(bf16)v1.x; fr[5]=(bf16)v1.y; fr[6]=(bf16)v1.z; fr[7]=(bf16)v1.w;
      *reinterpret_cast<bf16x8*>(&s_regA[(size_t)s * 8]) = fr;
    }
  }
  __syncthreads();   // B1

  // ---- GEMM1: Q = X(64x256) * Wq[head=w](256x32) ----
  {
    f32x4 acc[4][2];
    #pragma unroll
    for (int mt = 0; mt < 4; ++mt) { acc[mt][0] = (f32x4)0.f; acc[mt][1] = (f32x4)0.f; }
    const bf16x8* pQ = reinterpret_cast<const bf16x8*>(ws + OFF_Q);
    #pragma unroll
    for (int ks = 0; ks < 8; ++ks) {
      bf16x8 b0 = pQ[((w*8 + ks)*2 + 0)*64 + lane];
      bf16x8 b1 = pQ[((w*8 + ks)*2 + 1)*64 + lane];
      #pragma unroll
      for (int mt = 0; mt < 4; ++mt) {
        bf16x8 a = *reinterpret_cast<const bf16x8*>(&s_regA[((mt*8 + ks)*64 + lane)*8]);
        acc[mt][0] = MFMA16(a, b0, acc[mt][0]);
        acc[mt][1] = MFMA16(a, b1, acc[mt][1]);
      }
    }
    __syncthreads();   // B2: all xfrag reads done (q/attfrag overwrite regA)
    float bq0 = (float)s_bq[w*32 + lc], bq1 = (float)s_bq[w*32 + 16 + lc];
    #pragma unroll
    for (int mt = 0; mt < 4; ++mt)
      #pragma unroll
      for (int r = 0; r < 4; ++r) {
        int row = mt*16 + lr*4 + r;
        int sw = (row & 7) << 3;
        int c0 = (w*32 + lc) ^ sw;
        int c1 = (w*32 + 16 + lc) ^ sw;
        s_q[row*128 + c0] = (bf16)(acc[mt][0][r] + bq0);
        s_q[row*128 + c1] = (bf16)(acc[mt][1][r] + bq1);
      }
  }
  // no barrier: q written/read by the SAME wave (cols w*32..); intra-wave DS order

  // ---- Phase B: prototype attention; wave w = head w, lane = row ----
  {
    const int r = lane;
    const int h = w;
    const int swr = (r & 7) << 3;
    float q[32];
    #pragma unroll
    for (int g = 0; g < 4; ++g) {
      bf16x8 v = *reinterpret_cast<const bf16x8*>(&s_q[r*128 + ((h*32 + g*8) ^ swr)]);
      #pragma unroll
      for (int j = 0; j < 8; ++j) q[g*8 + j] = (float)v[j];
    }
    float u = s_diff[r];
    float up = u + 1e-8f;
    float mod = 1.f + s_fa[h]*up*up*s_ft[h];
    float sc[4];
    #pragma unroll
    for (int p = 0; p < 4; ++p) {
      float s = s_imp[h*4 + p];
      const float4* kp = reinterpret_cast<const float4*>(&s_pk[(h*4 + p)*32]);
      #pragma unroll
      for (int g = 0; g < 8; ++g) {
        float4 kv = kp[g];
        s = fmaf(q[g*4+0], kv.x, s); s = fmaf(q[g*4+1], kv.y, s);
        s = fmaf(q[g*4+2], kv.z, s); s = fmaf(q[g*4+3], kv.w, s);
      }
      sc[p] = s * mod * SCALE_F;
    }
    float mx = fmaxf(fmaxf(sc[0], sc[1]), fmaxf(sc[2], sc[3]));
    float e0 = fast_exp(sc[0]-mx), e1 = fast_exp(sc[1]-mx);
    float e2 = fast_exp(sc[2]-mx), e3 = fast_exp(sc[3]-mx);
    float inv = fast_rcp(e0+e1+e2+e3);
    e0 *= inv; e1 *= inv; e2 *= inv; e3 *= inv;
    const float4* p0 = reinterpret_cast<const float4*>(&s_pv[(h*4+0)*32]);
    const float4* p1 = reinterpret_cast<const float4*>(&s_pv[(h*4+1)*32]);
    const float4* p2 = reinterpret_cast<const float4*>(&s_pv[(h*4+2)*32]);
    const float4* p3 = reinterpret_cast<const float4*>(&s_pv[(h*4+3)*32]);
    const int mt = r >> 4, rl = r & 15;
    #pragma unroll
    for (int g = 0; g < 4; ++g) {
      float4 a0 = p0[g*2],   b0v = p0[g*2+1];
      float4 a1 = p1[g*2],   b1v = p1[g*2+1];
      float4 a2 = p2[g*2],   b2v = p2[g*2+1];
      float4 a3 = p3[g*2],   b3v = p3[g*2+1];
      bf16x8 av;
      av[0] = (bf16)(e0*a0.x + e1*a1.x + e2*a2.x + e3*a3.x);
      av[1] = (bf16)(e0*a0.y + e1*a1.y + e2*a2.y + e3*a3.y);
      av[2] = (bf16)(e0*a0.z + e1*a1.z + e2*a2.z + e3*a3.z);
      av[3] = (bf16)(e0*a0.w + e1*a1.w + e2*a2.w + e3*a3.w);
      av[4] = (bf16)(e0*b0v.x + e1*b1v.x + e2*b2v.x + e3*b3v.x);
      av[5] = (bf16)(e0*b0v.y + e1*b1v.y + e2*b2v.y + e3*b3v.y);
      av[6] = (bf16)(e0*b0v.z + e1*b1v.z + e2*b2v.z + e3*b3v.z);
      av[7] = (bf16)(e0*b0v.w + e1*b1v.w + e2*b2v.w + e3*b3v.w);
      *reinterpret_cast<bf16x8*>(&s_regA[(((w*4) + mt)*64 + g*16 + rl)*8]) = av;
    }
  }
  __syncthreads();   // B3a: all q reads done (combfrag will overwrite upper region)

  // ---- Wo-GEMM + per-head LN -> combfrag (upper 16KB) ----
  {
    const bf16x8* pO = reinterpret_cast<const bf16x8*>(ws + OFF_O);
    bf16x8 b0 = pO[(w*2 + 0)*64 + lane];
    bf16x8 b1 = pO[(w*2 + 1)*64 + lane];
    f32x4 acc[4][2];
    #pragma unroll
    for (int mt = 0; mt < 4; ++mt) { acc[mt][0] = (f32x4)0.f; acc[mt][1] = (f32x4)0.f; }
    #pragma unroll
    for (int mt = 0; mt < 4; ++mt) {
      bf16x8 a = *reinterpret_cast<const bf16x8*>(&s_regA[((w*4 + mt)*64 + lane)*8]);
      acc[mt][0] = MFMA16(a, b0, acc[mt][0]);
      acc[mt][1] = MFMA16(a, b1, acc[mt][1]);
    }
    float bo0 = (float)s_bo[w*32 + lc],  bo1 = (float)s_bo[w*32 + 16 + lc];
    float lg0 = (float)s_lng[w*32 + lc], lg1 = (float)s_lng[w*32 + 16 + lc];
    float lb0 = (float)s_lnb[w*32 + lc], lb1 = (float)s_lnb[w*32 + 16 + lc];
    #pragma unroll
    for (int mt = 0; mt < 4; ++mt)
      #pragma unroll
      for (int r = 0; r < 4; ++r) {
        float v0 = acc[mt][0][r] + bo0;
        float v1 = acc[mt][1][r] + bo1;
        float s = v0 + v1, sq = v0*v0 + v1*v1;
        s += __shfl_xor(s, 1, 64);  sq += __shfl_xor(sq, 1, 64);
        s += __shfl_xor(s, 2, 64);  sq += __shfl_xor(sq, 2, 64);
        s += __shfl_xor(s, 4, 64);  sq += __shfl_xor(sq, 4, 64);
        s += __shfl_xor(s, 8, 64);  sq += __shfl_xor(sq, 8, 64);
        float mean = s * (1.f/32.f);
        float var  = sq * (1.f/32.f) - mean*mean;
        float rstd = rsqrtf(var + 1e-5f);
        float n0 = (v0 - mean)*rstd*lg0 + lb0;
        float n1 = (v1 - mean)*rstd*lg1 + lb1;
        int rl = lr*4 + r;
        int base = 8192 + ((w*4 + mt)*64)*8;
        s_regA[base + (16*(lc >> 3)       + rl)*8 + (lane & 7)] = (bf16)n0;
        s_regA[base + (16*(2 + (lc >> 3)) + rl)*8 + (lane & 7)] = (bf16)n1;
      }
  }
  __syncthreads();   // B3b: combfrag ready (cross-wave)

  // ---- GEMM2 (row-partitioned): wave w computes out_pre[rows w*16..+16)][all 256 cols] ----
  bf16x8 opb[8];     // out_pre bf16: opb[nt>>1][(nt&1)*4 + r], nt = global col/16
  {
    const bf16x8* pF = reinterpret_cast<const bf16x8*>(ws + OFF_F);
    #pragma unroll
    for (int c4 = 0; c4 < 4; ++c4) {       // nt = c4*4 + n2
      f32x4 acc[4];
      #pragma unroll
      for (int n2 = 0; n2 < 4; ++n2) acc[n2] = (f32x4)0.f;
      #pragma unroll
      for (int ks = 0; ks < 4; ++ks) {
        bf16x8 a = *reinterpret_cast<const bf16x8*>(&s_regA[8192 + ((ks*4 + w)*64 + lane)*8]);
        #pragma unroll
        for (int n2 = 0; n2 < 4; ++n2)
          acc[n2] = MFMA16(a, pF[(ks*16 + c4*4 + n2)*64 + lane], acc[n2]);
      }
      #pragma unroll
      for (int n2 = 0; n2 < 4; ++n2) {
        int nt = c4*4 + n2;
        float bfv = (float)s_bf[nt*16 + lc];
        #pragma unroll
        for (int r = 0; r < 4; ++r)
          opb[nt >> 1][(nt & 1)*4 + r] = (bf16)(acc[n2][r] + bfv);
      }
    }
  }
  __syncthreads();   // B4: all combfrag reads done -> per-wave slices may claim full regA
  // ======== everything below is WAVE-LOCAL: zero barriers ========

  bf16* sw_ = s_regA + w * 4096;    // private 8KB slice (4096 bf16 elements)

  // ---- opfrag write: out_pre[16][256] -> A-frag layout (K=256 -> ks2=0..7) ----
  {
    #pragma unroll
    for (int nt = 0; nt < 16; ++nt) {
      int ks2 = nt >> 1;
      #pragma unroll
      for (int r = 0; r < 4; ++r) {
        int rowp = lr*4 + r;
        int lane2 = 16*((nt*2 + (lc >> 3)) & 3) + rowp;
        sw_[(ks2*64 + lane2)*8 + (lc & 7)] = opb[nt >> 1][(nt & 1)*4 + r];
      }
    }
  }

  // ---- GEMM3 (wave-local): hidden = relu(out_pre(16x256)*Wg1(256x64)+diff*wg1d+bg1) ----
  {
    f32x4 acc3[4];
    #pragma unroll
    for (int n = 0; n < 4; ++n) acc3[n] = (f32x4)0.f;
    const bf16x8* pG1 = reinterpret_cast<const bf16x8*>(ws + OFF_G1);
    #pragma unroll
    for (int ks2 = 0; ks2 < 8; ++ks2) {
      bf16x8 a = *reinterpret_cast<const bf16x8*>(&sw_[(ks2*64 + lane)*8]);
      #pragma unroll
      for (int n3 = 0; n3 < 4; ++n3)
        acc3[n3] = MFMA16(a, pG1[(ks2*4 + n3)*64 + lane], acc3[n3]);
    }
    float dfr[4];
    #pragma unroll
    for (int r = 0; r < 4; ++r) dfr[r] = s_diff[w*16 + lr*4 + r];
    // hfrag write over slice[0:1024) (opfrag fully read; intra-wave DS order)
    #pragma unroll
    for (int n3 = 0; n3 < 4; ++n3) {
      int col3 = n3*16 + lc;
      float b1v = s_bg1[col3], wdv = s_wg1d[col3];
      int ks4 = n3 >> 1;
      #pragma unroll
      for (int r = 0; r < 4; ++r) {
        int rowp = lr*4 + r;
        float hv = fmaxf(acc3[n3][r] + b1v + dfr[r]*wdv, 0.f);
        int lane2 = 16*((n3*2 + (lc >> 3)) & 3) + rowp;
        sw_[(ks4*64 + lane2)*8 + (lc & 7)] = (bf16)hv;
      }
    }
  }

  // ---- GEMM4 pass 1 (wave-local, nt-chunked): LN stats ----
  float mean4[4], rstd4[4];
  {
    const float* xr = x + (size_t)(row0 + w*16) * D;
    const bf16x8* pG2 = reinterpret_cast<const bf16x8*>(ws + OFF_G2);
    float s4[4] = {0.f,0.f,0.f,0.f}, q4[4] = {0.f,0.f,0.f,0.f};
    #pragma unroll
    for (int c4 = 0; c4 < 4; ++c4) {
      f32x4 acc4[4];
      #pragma unroll
      for (int n2 = 0; n2 < 4; ++n2) acc4[n2] = (f32x4)0.f;
      #pragma unroll
      for (int ks4 = 0; ks4 < 2; ++ks4) {
        bf16x8 a = *reinterpret_cast<const bf16x8*>(&sw_[(ks4*64 + lane)*8]);
        #pragma unroll
        for (int n2 = 0; n2 < 4; ++n2)
          acc4[n2] = MFMA16(a, pG2[(ks4*16 + c4*4 + n2)*64 + lane], acc4[n2]);
      }
      #pragma unroll
      for (int n2 = 0; n2 < 4; ++n2) {
        int nt = c4*4 + n2;
        int c = nt*16 + lc;
        float bg2v = (float)s_bg2[c];
        #pragma unroll
        for (int r = 0; r < 4; ++r) {
          int rowp = lr*4 + r;
          float z = acc4[n2][r] + bg2v;
          float gate = fast_rcp(1.f + fast_exp(-z));
          float op = (float)opb[nt >> 1][(nt & 1)*4 + r];
          float val = op*gate + xr[rowp*D + c];
          s4[r] += val; q4[r] = fmaf(val, val, q4[r]);
        }
      }
    }
    #pragma unroll
    for (int r = 0; r < 4; ++r) {
      float s = s4[r], q = q4[r];
      s += __shfl_xor(s, 1, 64);  q += __shfl_xor(q, 1, 64);
      s += __shfl_xor(s, 2, 64);  q += __shfl_xor(q, 2, 64);
      s += __shfl_xor(s, 4, 64);  q += __shfl_xor(q, 4, 64);
      s += __shfl_xor(s, 8, 64);  q += __shfl_xor(q, 8, 64);
      float mean = s * (1.f/256.f);
      float var  = q * (1.f/256.f) - mean*mean;
      mean4[r] = mean;
      rstd4[r] = rsqrtf(var + 1e-5f);
    }
  }

  // ---- GEMM4 pass 2 (recompute, bit-identical val) + scale + store ----
  {
    const float* xr = x + (size_t)(row0 + w*16) * D;
    float* orow = out + (size_t)(row0 + w*16) * D;
    const bf16x8* pG2 = reinterpret_cast<const bf16x8*>(ws + OFF_G2);
    #pragma unroll
    for (int c4 = 0; c4 < 4; ++c4) {
      f32x4 acc4[4];
      #pragma unroll
      for (int n2 = 0; n2 < 4; ++n2) acc4[n2] = (f32x4)0.f;
      #pragma unroll
      for (int ks4 = 0; ks4 < 2; ++ks4) {
        bf16x8 a = *reinterpret_cast<const bf16x8*>(&sw_[(ks4*64 + lane)*8]);
        #pragma unroll
        for (int n2 = 0; n2 < 4; ++n2)
          acc4[n2] = MFMA16(a, pG2[(ks4*16 + c4*4 + n2)*64 + lane], acc4[n2]);
      }
      #pragma unroll
      for (int n2 = 0; n2 < 4; ++n2) {
        int nt = c4*4 + n2;
        int c = nt*16 + lc;
        float bg2v = (float)s_bg2[c];
        float g_ = (float)s_lnFg[c], b_ = (float)s_lnFb[c];
        #pragma unroll
        for (int r = 0; r < 4; ++r) {
          int rowp = lr*4 + r;
          float z = acc4[n2][r] + bg2v;
          float gate = fast_rcp(1.f + fast_exp(-z));
          float op = (float)opb[nt >> 1][(nt & 1)*4 + r];
          float val = op*gate + xr[rowp*D + c];
          orow[rowp*D + c] = (val - mean4[r])*rstd4[r]*g_ + b_;
        }
      }
    }
  }
}

extern "C" void kernel_launch(void* const* d_in, const int* in_sizes, int n_in,
                              void* d_out, int out_size, void* d_ws, size_t ws_size,
                              hipStream_t stream) {
  (void)in_sizes; (void)n_in; (void)ws_size; (void)out_size;
  const float* x   = (const float*)d_in[0];
  const float* mp  = (const float*)d_in[1];
  const float* Wq  = (const float*)d_in[2];
  const float* bq  = (const float*)d_in[3];
  const float* pk  = (const float*)d_in[4];
  const float* pv  = (const float*)d_in[5];
  const float* imp = (const float*)d_in[6];
  const float* fa  = (const float*)d_in[7];
  const float* ft  = (const float*)d_in[8];
  const float* Wo  = (const float*)d_in[9];
  const float* bo  = (const float*)d_in[10];
  const float* lng = (const float*)d_in[11];
  const float* lnb = (const float*)d_in[12];
  const float* Wf  = (const float*)d_in[13];
  const float* bf  = (const float*)d_in[14];
  const float* Wg1 = (const float*)d_in[15];
  const float* bg1 = (const float*)d_in[16];
  const float* Wg2 = (const float*)d_in[17];
  const float* bg2 = (const float*)d_in[18];
  const float* lnFg= (const float*)d_in[19];
  const float* lnFb= (const float*)d_in[20];
  float* out = (float*)d_out;
  bf16* ws = (bf16*)d_ws;

  hipLaunchKernelGGL(prep_kernel, dim3((NPACK + 255)/256), dim3(256), 0, stream,
                     Wq, Wf, Wg1, Wg2, Wo, ws);
  hipLaunchKernelGGL(faiia_kernel, dim3(NROWS_TOT / ROWS), dim3(256), 0, stream,
                     x, mp, bq, pk, pv, imp, fa, ft, bo, lng, lnb,
                     bf, Wg1, bg1, bg2, lnFg, lnFb, ws, out);
}

// Round 12
// 229.929 us; speedup vs baseline: 2.8280x; 2.0543x over previous
//
#include <hip/hip_runtime.h>
#include <math.h>

typedef __bf16 bf16;
typedef __bf16 bf16x8 __attribute__((ext_vector_type(8)));
typedef float f32x4 __attribute__((ext_vector_type(4)));

#define MFMA16(a,b,c) __builtin_amdgcn_mfma_f32_16x16x32_bf16((a),(b),(c),0,0,0)

#define D 256
#define H 4
#define A 32
#define P 4
#define HA 128
#define RHID 64
#define ROWS 64
#define NROWS_TOT 262144
#define SCALE_F 0.17677669529663687f

// ws offsets in bf16 elements
#define OFF_Q  0
#define OFF_F  32768
#define OFF_G1 65536
#define OFF_G2 81920
#define OFF_O  98304
#define NPACK  102400

__device__ __forceinline__ float fast_exp(float x) { return __expf(x); }
__device__ __forceinline__ float fast_rcp(float x) { return __builtin_amdgcn_rcpf(x); }

// ---------------- weight prepack: f32 -> bf16 in MFMA B-fragment order ----------------
// B-fragment for 16x16x32: lane l holds col n = l&15, k = (l>>4)*8 + j (j=0..7, contiguous)
__global__ __launch_bounds__(256)
void prep_kernel(const float* __restrict__ Wq, const float* __restrict__ Wf,
                 const float* __restrict__ Wg1, const float* __restrict__ Wg2,
                 const float* __restrict__ Wo, bf16* __restrict__ ws)
{
  int i = blockIdx.x * 256 + threadIdx.x;
  if (i >= NPACK) return;
  float v;
  if (i < OFF_F) {              // packQ [h(4)][ks(8)][nt(2)][l(64)][j(8)], K=256,N=32 per head
    int j = i & 7, l = (i >> 3) & 63, nt = (i >> 9) & 1, ks = (i >> 10) & 7, h = i >> 13;
    int k = ks * 32 + (l >> 4) * 8 + j, n = nt * 16 + (l & 15);
    v = Wq[(h * 256 + k) * 32 + n];
  } else if (i < OFF_G1) {      // packF [ks(4)][gnt(16)][l][j], K=128,N=256
    int ii = i - OFF_F;
    int j = ii & 7, l = (ii >> 3) & 63, g = (ii >> 9) & 15, ks = ii >> 13;
    int k = ks * 32 + (l >> 4) * 8 + j, n = g * 16 + (l & 15);
    v = Wf[k * 256 + n];
  } else if (i < OFF_G2) {      // packG1 [ks(8)][nt(4)][l][j], K=256,N=64 (row 256 added via s_wg1d)
    int ii = i - OFF_G1;
    int j = ii & 7, l = (ii >> 3) & 63, nt = (ii >> 9) & 3, ks = ii >> 11;
    int k = ks * 32 + (l >> 4) * 8 + j, n = nt * 16 + (l & 15);
    v = Wg1[k * 64 + n];
  } else if (i < OFF_O) {       // packG2 [ks(2)][gnt(16)][l][j], K=64,N=256
    int ii = i - OFF_G2;
    int j = ii & 7, l = (ii >> 3) & 63, g = (ii >> 9) & 15, ks = ii >> 13;
    int k = ks * 32 + (l >> 4) * 8 + j, n = g * 16 + (l & 15);
    v = Wg2[k * 256 + n];
  } else {                      // packO [h(4)][nt(2)][l][j], K=32,N=32 per head
    int ii = i - OFF_O;
    int j = ii & 7, l = (ii >> 3) & 63, nt = (ii >> 9) & 1, h = ii >> 10;
    int k = (l >> 4) * 8 + j, n = nt * 16 + (l & 15);
    v = Wo[(h * 32 + k) * 32 + n];
  }
  ws[i] = (bf16)v;
}

// ---------------- fused main kernel: 64 rows/block, 4 waves, 5 MFMA GEMMs ----------------
// Best-known configuration (R5, 229.7 us, 13.7x over f32 baseline).
// Structural constraint documented over R3..R11: live state needs ~128 arch + ~64-128
// accum regs (unified file) -> 2 waves/SIMD hard cap; any tighter __launch_bounds__
// makes the compiler spill catastrophically (R3/R6/R10). Barrier count (12->6->5),
// LDS occupancy (2->4 blocks/CU), and wave-local restructures are all measured null
// or negative. LDS ~40KB; __launch_bounds__(256,2) is the only no-spill setting.
__global__ __launch_bounds__(256, 2)
void faiia_kernel(const float* __restrict__ x, const float* __restrict__ mp,
    const float* __restrict__ bq, const float* __restrict__ pk,
    const float* __restrict__ pv, const float* __restrict__ imp,
    const float* __restrict__ fa, const float* __restrict__ ft,
    const float* __restrict__ bo, const float* __restrict__ lng,
    const float* __restrict__ lnb, const float* __restrict__ bfb,
    const float* __restrict__ Wg1, const float* __restrict__ bg1,
    const float* __restrict__ bg2, const float* __restrict__ lnFg,
    const float* __restrict__ lnFb, const bf16* __restrict__ ws,
    float* __restrict__ out)
{
  // region A (32KB), multi-use timeline:
  //   xfrag(full) -> s_q(upper, swizzled) -> attfrag(lower) -> combfrag(upper)
  //   -> opfrag(full) -> hidden frag (bytes 0..8191) + LN scratch (bytes 8192..10751)
  __shared__ __attribute__((aligned(16))) bf16 s_regA[16384];
  __shared__ float s_pk[H*P*A], s_pv[H*P*A], s_imp[H*P], s_fa[H], s_ft[H];
  __shared__ bf16 s_bq[HA], s_bo[HA], s_lng[HA], s_lnb[HA];
  __shared__ bf16 s_bf[D], s_bg2[D], s_lnFg[D], s_lnFb[D];
  __shared__ float s_bg1[RHID], s_wg1d[RHID];
  __shared__ float s_diff[ROWS];

  bf16* s_q = s_regA + 8192;                                // upper 16KB of region A
  float* s_lnsum = reinterpret_cast<float*>(s_regA + 4096); // bytes 8192.. (dead during GEMM4)
  float* s_lnsq  = s_lnsum + 256;
  float* s_rmean = s_lnsq + 256;
  float* s_rrstd = s_rmean + 64;

  const int t = threadIdx.x;
  const int lane = t & 63;
  const int w = t >> 6;           // wave id
  const int lr = lane >> 4;       // row-group 0..3
  const int lc = lane & 15;       // col-in-tile
  const int row0 = blockIdx.x * ROWS;

  // ---- stage small constants ----
  for (int i = t; i < H*P*A; i += 256) { s_pk[i] = pk[i]; s_pv[i] = pv[i]; }
  if (t < H*P) s_imp[t] = imp[t];
  if (t < H) { s_fa[t] = fa[t]; s_ft[t] = ft[t]; }
  if (t < HA) { s_bq[t] = (bf16)bq[t]; s_bo[t] = (bf16)bo[t];
                s_lng[t] = (bf16)lng[t]; s_lnb[t] = (bf16)lnb[t]; }
  s_bf[t] = (bf16)bfb[t]; s_bg2[t] = (bf16)bg2[t];
  s_lnFg[t] = (bf16)lnFg[t]; s_lnFb[t] = (bf16)lnFb[t];
  if (t < RHID) { s_bg1[t] = bg1[t]; s_wg1d[t] = Wg1[256*RHID + t]; }
  if (t < ROWS) { float m = mp[row0 + t]; s_diff[t] = 1.f - 2.f*fabsf(m - 0.5f); }

  // ---- stage x -> bf16 A-fragments: slot s = (mt*8+ks)*64 + l ----
  {
    const float* xbase = x + (size_t)row0 * D;
    #pragma unroll
    for (int i = 0; i < 8; ++i) {
      int s = t + 256*i;
      int l = s & 63, ks = (s >> 6) & 7, mt = s >> 9;
      int row = mt*16 + (l & 15);
      int k0 = ks*32 + ((l >> 4) & 3)*8;
      const float* xp = xbase + row*D + k0;
      float4 v0 = *reinterpret_cast<const float4*>(xp);
      float4 v1 = *reinterpret_cast<const float4*>(xp + 4);
      bf16x8 fr;
      fr[0]=(bf16)v0.x; fr[1]=(bf16)v0.y; fr[2]=(bf16)v0.z; fr[3]=(bf16)v0.w;
      fr[4]=(bf16)v1.x; fr[5]=(bf16)v1.y; fr[6]=(bf16)v1.z; fr[7]=(bf16)v1.w;
      *reinterpret_cast<bf16x8*>(&s_regA[(size_t)s * 8]) = fr;
    }
  }
  __syncthreads();

  // ---- GEMM1: Q = X(64x256) * Wq[head=w](256x32); wave w computes head w ----
  {
    f32x4 acc[4][2];
    #pragma unroll
    for (int mt = 0; mt < 4; ++mt) { acc[mt][0] = (f32x4)0.f; acc[mt][1] = (f32x4)0.f; }
    const bf16x8* pQ = reinterpret_cast<const bf16x8*>(ws + OFF_Q);
    #pragma unroll
    for (int ks = 0; ks < 8; ++ks) {
      bf16x8 b0 = pQ[((w*8 + ks)*2 + 0)*64 + lane];
      bf16x8 b1 = pQ[((w*8 + ks)*2 + 1)*64 + lane];
      #pragma unroll
      for (int mt = 0; mt < 4; ++mt) {
        bf16x8 a = *reinterpret_cast<const bf16x8*>(&s_regA[((mt*8 + ks)*64 + lane)*8]);
        acc[mt][0] = MFMA16(a, b0, acc[mt][0]);
        acc[mt][1] = MFMA16(a, b1, acc[mt][1]);
      }
    }
    __syncthreads();   // all xfrag reads done before s_q overwrites upper 16KB
    float bq0 = (float)s_bq[w*32 + lc], bq1 = (float)s_bq[w*32 + 16 + lc];
    #pragma unroll
    for (int mt = 0; mt < 4; ++mt)
      #pragma unroll
      for (int r = 0; r < 4; ++r) {
        int row = mt*16 + lr*4 + r;
        int sw = (row & 7) << 3;                 // XOR swizzle (bf16 elements)
        int c0 = (w*32 + lc) ^ sw;
        int c1 = (w*32 + 16 + lc) ^ sw;
        s_q[row*128 + c0] = (bf16)(acc[mt][0][r] + bq0);
        s_q[row*128 + c1] = (bf16)(acc[mt][1][r] + bq1);
      }
  }
  __syncthreads();

  // ---- Phase B: prototype attention; wave w = head w, lane = row ----
  // pk/pv reads are wave-uniform (broadcast); q reads swizzle-spread across banks.
  {
    const int r = lane;
    const int h = w;
    const int swr = (r & 7) << 3;
    float q[32];
    #pragma unroll
    for (int g = 0; g < 4; ++g) {
      int c0 = (h*32 + g*8) ^ swr;               // 8-aligned: XOR flips bits >=3 only
      bf16x8 v = *reinterpret_cast<const bf16x8*>(&s_q[r*128 + c0]);
      #pragma unroll
      for (int j = 0; j < 8; ++j) q[g*8 + j] = (float)v[j];
    }
    float u = s_diff[r];
    float up = u + 1e-8f;
    float mod = 1.f + s_fa[h]*up*up*s_ft[h];
    float sc[4];
    #pragma unroll
    for (int p = 0; p < 4; ++p) {
      float s = s_imp[h*4 + p];
      const float4* kp = reinterpret_cast<const float4*>(&s_pk[(h*4 + p)*32]);
      #pragma unroll
      for (int g = 0; g < 8; ++g) {
        float4 kv = kp[g];
        s = fmaf(q[g*4+0], kv.x, s); s = fmaf(q[g*4+1], kv.y, s);
        s = fmaf(q[g*4+2], kv.z, s); s = fmaf(q[g*4+3], kv.w, s);
      }
      sc[p] = s * mod * SCALE_F;
    }
    float mx = fmaxf(fmaxf(sc[0], sc[1]), fmaxf(sc[2], sc[3]));
    float e0 = fast_exp(sc[0]-mx), e1 = fast_exp(sc[1]-mx);
    float e2 = fast_exp(sc[2]-mx), e3 = fast_exp(sc[3]-mx);
    float inv = fast_rcp(e0+e1+e2+e3);
    e0 *= inv; e1 *= inv; e2 *= inv; e3 *= inv;
    const float4* p0 = reinterpret_cast<const float4*>(&s_pv[(h*4+0)*32]);
    const float4* p1 = reinterpret_cast<const float4*>(&s_pv[(h*4+1)*32]);
    const float4* p2 = reinterpret_cast<const float4*>(&s_pv[(h*4+2)*32]);
    const float4* p3 = reinterpret_cast<const float4*>(&s_pv[(h*4+3)*32]);
    const int mt = r >> 4, rl = r & 15;
    #pragma unroll
    for (int g = 0; g < 4; ++g) {
      float4 a0 = p0[g*2],   b0v = p0[g*2+1];
      float4 a1 = p1[g*2],   b1v = p1[g*2+1];
      float4 a2 = p2[g*2],   b2v = p2[g*2+1];
      float4 a3 = p3[g*2],   b3v = p3[g*2+1];
      bf16x8 av;
      av[0] = (bf16)(e0*a0.x + e1*a1.x + e2*a2.x + e3*a3.x);
      av[1] = (bf16)(e0*a0.y + e1*a1.y + e2*a2.y + e3*a3.y);
      av[2] = (bf16)(e0*a0.z + e1*a1.z + e2*a2.z + e3*a3.z);
      av[3] = (bf16)(e0*a0.w + e1*a1.w + e2*a2.w + e3*a3.w);
      av[4] = (bf16)(e0*b0v.x + e1*b1v.x + e2*b2v.x + e3*b3v.x);
      av[5] = (bf16)(e0*b0v.y + e1*b1v.y + e2*b2v.y + e3*b3v.y);
      av[6] = (bf16)(e0*b0v.z + e1*b1v.z + e2*b2v.z + e3*b3v.z);
      av[7] = (bf16)(e0*b0v.w + e1*b1v.w + e2*b2v.w + e3*b3v.w);
      // attfrag[h*4+mt][lane' = g*16 + rl][j]  (wave-local slice)
      *reinterpret_cast<bf16x8*>(&s_regA[(((h*4) + mt)*64 + g*16 + rl)*8]) = av;
    }
  }
  __syncthreads();   // q region (upper) must be fully read before combfrag overwrites it

  // ---- Wo-GEMM + per-head LN; wave w = head w; writes combfrag (upper 16KB) ----
  {
    f32x4 acc[4][2];
    #pragma unroll
    for (int mt = 0; mt < 4; ++mt) { acc[mt][0] = (f32x4)0.f; acc[mt][1] = (f32x4)0.f; }
    const bf16x8* pO = reinterpret_cast<const bf16x8*>(ws + OFF_O);
    bf16x8 b0 = pO[(w*2 + 0)*64 + lane];
    bf16x8 b1 = pO[(w*2 + 1)*64 + lane];
    #pragma unroll
    for (int mt = 0; mt < 4; ++mt) {
      bf16x8 a = *reinterpret_cast<const bf16x8*>(&s_regA[((w*4 + mt)*64 + lane)*8]);
      acc[mt][0] = MFMA16(a, b0, acc[mt][0]);
      acc[mt][1] = MFMA16(a, b1, acc[mt][1]);
    }
    float bo0 = (float)s_bo[w*32 + lc],  bo1 = (float)s_bo[w*32 + 16 + lc];
    float lg0 = (float)s_lng[w*32 + lc], lg1 = (float)s_lng[w*32 + 16 + lc];
    float lb0 = (float)s_lnb[w*32 + lc], lb1 = (float)s_lnb[w*32 + 16 + lc];
    #pragma unroll
    for (int mt = 0; mt < 4; ++mt)
      #pragma unroll
      for (int r = 0; r < 4; ++r) {
        float v0 = acc[mt][0][r] + bo0;
        float v1 = acc[mt][1][r] + bo1;
        float s = v0 + v1, sq = v0*v0 + v1*v1;
        s += __shfl_xor(s, 1, 64);  sq += __shfl_xor(sq, 1, 64);
        s += __shfl_xor(s, 2, 64);  sq += __shfl_xor(sq, 2, 64);
        s += __shfl_xor(s, 4, 64);  sq += __shfl_xor(sq, 4, 64);
        s += __shfl_xor(s, 8, 64);  sq += __shfl_xor(sq, 8, 64);
        float mean = s * (1.f/32.f);
        float var  = sq * (1.f/32.f) - mean*mean;
        float rstd = rsqrtf(var + 1e-5f);
        float n0 = (v0 - mean)*rstd*lg0 + lb0;
        float n1 = (v1 - mean)*rstd*lg1 + lb1;
        int rl = lr*4 + r;
        int base = 8192 + ((w*4 + mt)*64)*8;
        s_regA[base + (16*(lc >> 3)       + rl)*8 + (lane & 7)] = (bf16)n0;
        s_regA[base + (16*(2 + (lc >> 3)) + rl)*8 + (lane & 7)] = (bf16)n1;
      }
  }
  __syncthreads();

  // ---- GEMM2: out_pre = combined(64x128) * Wf(128x256); wave w -> cols [64w,64w+64) ----
  f32x4 acc2[4][4];
  {
    #pragma unroll
    for (int mt = 0; mt < 4; ++mt)
      #pragma unroll
      for (int nt = 0; nt < 4; ++nt) acc2[mt][nt] = (f32x4)0.f;
    const bf16x8* pF = reinterpret_cast<const bf16x8*>(ws + OFF_F);
    #pragma unroll
    for (int ks = 0; ks < 4; ++ks) {
      bf16x8 a[4], bb[4];
      #pragma unroll
      for (int mt = 0; mt < 4; ++mt)
        a[mt] = *reinterpret_cast<const bf16x8*>(&s_regA[8192 + ((ks*4 + mt)*64 + lane)*8]);
      #pragma unroll
      for (int nt = 0; nt < 4; ++nt)
        bb[nt] = pF[(ks*16 + w*4 + nt)*64 + lane];
      #pragma unroll
      for (int mt = 0; mt < 4; ++mt)
        #pragma unroll
        for (int nt = 0; nt < 4; ++nt)
          acc2[mt][nt] = MFMA16(a[mt], bb[nt], acc2[mt][nt]);
    }
    #pragma unroll
    for (int nt = 0; nt < 4; ++nt) {
      float bfv = (float)s_bf[w*64 + nt*16 + lc];
      #pragma unroll
      for (int mt = 0; mt < 4; ++mt)
        #pragma unroll
        for (int r = 0; r < 4; ++r) acc2[mt][nt][r] += bfv;
    }
  }
  __syncthreads();   // all combfrag reads done before opfrag overwrites region A
  {
    #pragma unroll
    for (int mt = 0; mt < 4; ++mt)
      #pragma unroll
      for (int nt = 0; nt < 4; ++nt) {
        int ks3 = w*2 + (nt >> 1);
        #pragma unroll
        for (int r = 0; r < 4; ++r) {
          int lane2 = 16*((nt & 1)*2 + (lc >> 3)) + (lr*4 + r);
          s_regA[((ks3*4 + mt)*64 + lane2)*8 + (lane & 7)] = (bf16)acc2[mt][nt][r];
        }
      }
  }
  __syncthreads();

  // ---- GEMM3: hidden = relu(out_pre(64x256)*Wg1(256x64) + diff*wg1d + bg1); wave w -> cols [16w,16w+16) ----
  {
    f32x4 acc3[4];
    #pragma unroll
    for (int mt = 0; mt < 4; ++mt) acc3[mt] = (f32x4)0.f;
    const bf16x8* pG1 = reinterpret_cast<const bf16x8*>(ws + OFF_G1);
    #pragma unroll
    for (int ks = 0; ks < 8; ++ks) {
      bf16x8 b = pG1[(ks*4 + w)*64 + lane];
      #pragma unroll
      for (int mt = 0; mt < 4; ++mt) {
        bf16x8 a = *reinterpret_cast<const bf16x8*>(&s_regA[((ks*4 + mt)*64 + lane)*8]);
        acc3[mt] = MFMA16(a, b, acc3[mt]);
      }
    }
    int col3 = w*16 + lc;
    float b1v = s_bg1[col3], wdv = s_wg1d[col3];
    #pragma unroll
    for (int mt = 0; mt < 4; ++mt)
      #pragma unroll
      for (int r = 0; r < 4; ++r) {
        int row = mt*16 + lr*4 + r;
        acc3[mt][r] = fmaxf(acc3[mt][r] + b1v + s_diff[row]*wdv, 0.f);
      }
    __syncthreads();   // all opfrag reads done before hidden frag overwrites regA[0:8KB]
    #pragma unroll
    for (int mt = 0; mt < 4; ++mt)
      #pragma unroll
      for (int r = 0; r < 4; ++r)
        s_regA[(((w >> 1)*4 + mt)*64 + 16*((w & 1)*2 + (lc >> 3)) + (lr*4 + r))*8 + (lane & 7)] = (bf16)acc3[mt][r];
  }
  __syncthreads();

  // ---- GEMM4 (two nt-halves to cap live registers): gate = sigmoid(...); val = out_pre*gate + x ----
  {
    const float* xbase = x + (size_t)row0 * D;
    const bf16x8* pG2 = reinterpret_cast<const bf16x8*>(ws + OFF_G2);
    #pragma unroll
    for (int half = 0; half < 2; ++half) {
      f32x4 acc4[4][2];
      #pragma unroll
      for (int mt = 0; mt < 4; ++mt) { acc4[mt][0] = (f32x4)0.f; acc4[mt][1] = (f32x4)0.f; }
      #pragma unroll
      for (int ks = 0; ks < 2; ++ks) {
        bf16x8 a[4], bb[2];
        #pragma unroll
        for (int mt = 0; mt < 4; ++mt)
          a[mt] = *reinterpret_cast<const bf16x8*>(&s_regA[((ks*4 + mt)*64 + lane)*8]);
        #pragma unroll
        for (int n2 = 0; n2 < 2; ++n2)
          bb[n2] = pG2[(ks*16 + w*4 + half*2 + n2)*64 + lane];
        #pragma unroll
        for (int mt = 0; mt < 4; ++mt)
          #pragma unroll
          for (int n2 = 0; n2 < 2; ++n2)
            acc4[mt][n2] = MFMA16(a[mt], bb[n2], acc4[mt][n2]);
      }
      #pragma unroll
      for (int n2 = 0; n2 < 2; ++n2) {
        int nt = half*2 + n2;
        int c = w*64 + nt*16 + lc;
        float bg2v = (float)s_bg2[c];
        #pragma unroll
        for (int mt = 0; mt < 4; ++mt)
          #pragma unroll
          for (int r = 0; r < 4; ++r) {
            int row = mt*16 + lr*4 + r;
            float z = acc4[mt][n2][r] + bg2v;
            float gate = fast_rcp(1.f + fast_exp(-z));
            acc2[mt][nt][r] = acc2[mt][nt][r]*gate + xbase[row*D + c];
          }
      }
    }
  }
  // LN scratch (bytes 8192..) is disjoint from hidden frag (bytes 0..8191): no barrier needed.

  // ---- final LN partials (per row over this wave's 64 cols) ----
  {
    #pragma unroll
    for (int mt = 0; mt < 4; ++mt)
      #pragma unroll
      for (int r = 0; r < 4; ++r) {
        float s = 0.f, sq = 0.f;
        #pragma unroll
        for (int nt = 0; nt < 4; ++nt) {
          float v = acc2[mt][nt][r];
          s += v; sq = fmaf(v, v, sq);
        }
        s += __shfl_xor(s, 1, 64);  sq += __shfl_xor(sq, 1, 64);
        s += __shfl_xor(s, 2, 64);  sq += __shfl_xor(sq, 2, 64);
        s += __shfl_xor(s, 4, 64);  sq += __shfl_xor(sq, 4, 64);
        s += __shfl_xor(s, 8, 64);  sq += __shfl_xor(sq, 8, 64);
        if (lc == 0) {
          int row = mt*16 + lr*4 + r;
          s_lnsum[row*4 + w] = s;
          s_lnsq[row*4 + w]  = sq;
        }
      }
  }
  __syncthreads();
  if (t < ROWS) {
    float s  = s_lnsum[t*4] + s_lnsum[t*4+1] + s_lnsum[t*4+2] + s_lnsum[t*4+3];
    float sq = s_lnsq[t*4]  + s_lnsq[t*4+1]  + s_lnsq[t*4+2]  + s_lnsq[t*4+3];
    float mean = s * (1.f/256.f);
    float var  = sq * (1.f/256.f) - mean*mean;
    s_rmean[t] = mean;
    s_rrstd[t] = rsqrtf(var + 1e-5f);
  }
  __syncthreads();
  {
    float* obase = out + (size_t)row0 * D;
    #pragma unroll
    for (int mt = 0; mt < 4; ++mt)
      #pragma unroll
      for (int r = 0; r < 4; ++r) {
        int row = mt*16 + lr*4 + r;
        float mean = s_rmean[row], rstd = s_rrstd[row];
        #pragma unroll
        for (int nt = 0; nt < 4; ++nt) {
          int c = w*64 + nt*16 + lc;
          obase[row*D + c] = (acc2[mt][nt][r] - mean)*rstd*(float)s_lnFg[c] + (float)s_lnFb[c];
        }
      }
  }
}

extern "C" void kernel_launch(void* const* d_in, const int* in_sizes, int n_in,
                              void* d_out, int out_size, void* d_ws, size_t ws_size,
                              hipStream_t stream) {
  (void)in_sizes; (void)n_in; (void)ws_size; (void)out_size;
  const float* x   = (const float*)d_in[0];
  const float* mp  = (const float*)d_in[1];
  const float* Wq  = (const float*)d_in[2];
  const float* bq  = (const float*)d_in[3];
  const float* pk  = (const float*)d_in[4];
  const float* pv  = (const float*)d_in[5];
  const float* imp = (const float*)d_in[6];
  const float* fa  = (const float*)d_in[7];
  const float* ft  = (const float*)d_in[8];
  const float* Wo  = (const float*)d_in[9];
  const float* bo  = (const float*)d_in[10];
  const float* lng = (const float*)d_in[11];
  const float* lnb = (const float*)d_in[12];
  const float* Wf  = (const float*)d_in[13];
  const float* bf  = (const float*)d_in[14];
  const float* Wg1 = (const float*)d_in[15];
  const float* bg1 = (const float*)d_in[16];
  const float* Wg2 = (const float*)d_in[17];
  const float* bg2 = (const float*)d_in[18];
  const float* lnFg= (const float*)d_in[19];
  const float* lnFb= (const float*)d_in[20];
  float* out = (float*)d_out;
  bf16* ws = (bf16*)d_ws;

  hipLaunchKernelGGL(prep_kernel, dim3((NPACK + 255)/256), dim3(256), 0, stream,
                     Wq, Wf, Wg1, Wg2, Wo, ws);
  hipLaunchKernelGGL(faiia_kernel, dim3(NROWS_TOT / ROWS), dim3(256), 0, stream,
                     x, mp, bq, pk, pv, imp, fa, ft, bo, lng, lnb,
                     bf, Wg1, bg1, bg2, lnFg, lnFb, ws, out);
}